// Round 15
// baseline (493.169 us; speedup 1.0000x reference)
//
#include <hip/hip_runtime.h>
#include <math.h>

#define H_ 152
#define W_ 272
#define HW_ 41344
#define W4_ 68       /* W_/4 */
#define HW4_ 10336   /* HW_/4 */
#define B_ 16
#define G_ 8
#define CG_ 16
#define NG_ 128   /* B*G */
#define PC_ 2048  /* NG*CG */
#define S_ 4
#define EPSV 1e-5f
#define NTILE_ 162   /* ceil(HW4_/64) */

__device__ __forceinline__ float sigf(float v){ return 1.0f/(1.0f+__expf(-v)); }

// ---------------- Kernel 1: per-plane row means (xh) and col means (xw) ----
__global__ void k_stats1(const float* __restrict__ x, float* __restrict__ xh,
                         float* __restrict__ xw){
  int plane = blockIdx.x;
  const float* xp = x + (size_t)plane*HW_;
  int tid = threadIdx.x, wv = tid>>6, lane = tid&63;
  float ca0[4] = {0,0,0,0};
  float ca1[4] = {0,0,0,0};
  for (int h = wv; h < H_; h += 4){
    const float4* row = (const float4*)(xp + h*W_);
    float4 v0 = row[lane];
    float rs = v0.x+v0.y+v0.z+v0.w;
    ca0[0]+=v0.x; ca0[1]+=v0.y; ca0[2]+=v0.z; ca0[3]+=v0.w;
    if (lane < 4){
      float4 v1 = row[64+lane];
      rs += v1.x+v1.y+v1.z+v1.w;
      ca1[0]+=v1.x; ca1[1]+=v1.y; ca1[2]+=v1.z; ca1[3]+=v1.w;
    }
    #pragma unroll
    for (int off=32; off>0; off>>=1) rs += __shfl_down(rs, off, 64);
    if (lane==0) xh[plane*H_ + h] = rs * (1.0f/W_);
  }
  __shared__ float cs[4][W_];
  #pragma unroll
  for (int j=0;j<4;++j) cs[wv][lane*4+j] = ca0[j];
  if (lane<4){
    #pragma unroll
    for (int j=0;j<4;++j) cs[wv][256+lane*4+j] = ca1[j];
  }
  __syncthreads();
  for (int w=tid; w<W_; w+=256)
    xw[plane*W_ + w] = (cs[0][w]+cs[1][w]+cs[2][w]+cs[3][w]) * (1.0f/H_);
}

// ---------------- Kernel 2: sh/sw gates, x21 softmax, collapsed filter -----
__global__ void k_prep(const float* __restrict__ x,
                       const float* __restrict__ xh, const float* __restrict__ xw,
                       const float* __restrict__ w1, const float* __restrict__ b1,
                       const float* __restrict__ w3, const float* __restrict__ b3,
                       const float* __restrict__ gnb,
                       float* __restrict__ sh, float* __restrict__ sw,
                       float* __restrict__ x21, float* __restrict__ wsum,
                       float* __restrict__ bsum){
  int bg = blockIdx.x; int tid = threadIdx.x;
  __shared__ float xhl[CG_][H_];
  __shared__ float xwl[CG_][W_];
  __shared__ float w1l[CG_*CG_];
  __shared__ float b1l[CG_];
  __shared__ float Tk[CG_], R0[CG_], RL[CG_], C0[CG_], CL[CG_];
  __shared__ float crn[CG_][4];
  __shared__ float mx2[CG_], x11l[CG_];
  for (int i=tid;i<CG_*CG_;i+=256) w1l[i]=w1[i];
  if (tid < CG_) b1l[tid]=b1[tid];
  for (int i=tid;i<CG_*H_;i+=256){ int c=i/H_, h=i%H_; xhl[c][h]=xh[(bg*CG_+c)*H_+h]; }
  for (int i=tid;i<CG_*W_;i+=256){ int c=i/W_, w=i%W_; xwl[c][w]=xw[(bg*CG_+c)*W_+w]; }
  __syncthreads();
  // 1x1 conv + sigmoid on the row/col mean vectors
  for (int i=tid;i<CG_*H_;i+=256){
    int c=i/H_, h=i%H_;
    float a=b1l[c];
    #pragma unroll
    for (int k=0;k<CG_;++k) a += w1l[c*CG_+k]*xhl[k][h];
    sh[(bg*CG_+c)*H_+h] = sigf(a);
  }
  for (int i=tid;i<CG_*W_;i+=256){
    int c=i/W_, w=i%W_;
    float a=b1l[c];
    #pragma unroll
    for (int k=0;k<CG_;++k) a += w1l[c*CG_+k]*xwl[k][w];
    sw[(bg*CG_+c)*W_+w] = sigf(a);
  }
  // exact mean of 3x3-conv output via total/row/col/corner sums
  if (tid < CG_){
    int k=tid;
    float t=0;
    for (int h=0;h<H_;++h) t += xhl[k][h];
    Tk[k] = t * W_;
    R0[k] = xhl[k][0]*W_; RL[k]=xhl[k][H_-1]*W_;
    C0[k] = xwl[k][0]*H_; CL[k]=xwl[k][W_-1]*H_;
    const float* xp = x + (size_t)(bg*CG_+k)*HW_;
    crn[k][0]=xp[0]; crn[k][1]=xp[W_-1];
    crn[k][2]=xp[(size_t)(H_-1)*W_]; crn[k][3]=xp[(size_t)(H_-1)*W_+W_-1];
  }
  __syncthreads();
  if (tid < CG_){
    int c=tid;
    float acc=0;
    for (int k=0;k<CG_;++k){
      #pragma unroll
      for (int ky=0;ky<3;++ky){ int dy=ky-1;
        #pragma unroll
        for (int kx=0;kx<3;++kx){ int dx=kx-1;
          float s = Tk[k];
          if (dy==1) s -= R0[k]; else if (dy==-1) s -= RL[k];
          if (dx==1) s -= C0[k]; else if (dx==-1) s -= CL[k];
          if (dy==1 && dx==1) s += crn[k][0];
          else if (dy==1 && dx==-1) s += crn[k][1];
          else if (dy==-1 && dx==1) s += crn[k][2];
          else if (dy==-1 && dx==-1) s += crn[k][3];
          acc += w3[((c*CG_+k)*3+ky)*3+kx]*s;
        }
      }
    }
    mx2[c] = b3[c] + acc*(1.0f/HW_);
  }
  __syncthreads();
  if (tid==0){
    float m=mx2[0]; for (int c=1;c<CG_;++c) m=fmaxf(m,mx2[c]);
    float ssum=0.f; float e[CG_];
    for (int c=0;c<CG_;++c){ e[c]=__expf(mx2[c]-m); ssum+=e[c]; }
    for (int c=0;c<CG_;++c) x21[bg*CG_+c]=e[c]/ssum;
    // x11 = softmax(mean(x1)) = softmax(gn_b) exactly
    float m2=gnb[0]; for (int c=1;c<CG_;++c) m2=fmaxf(m2,gnb[c]);
    float s2=0.f; float e2[CG_];
    for (int c=0;c<CG_;++c){ e2[c]=__expf(gnb[c]-m2); s2+=e2[c]; }
    float bs=0.f;
    for (int c=0;c<CG_;++c){ x11l[c]=e2[c]/s2; bs += (e2[c]/s2)*b3[c]; }
    bsum[bg]=bs;
  }
  __syncthreads();
  for (int i=tid;i<CG_*9;i+=256){
    int k=i/9, r=i%9; int ky=r/3, kx=r%3;
    float a=0;
    for (int c=0;c<CG_;++c) a += x11l[c]*w3[((c*CG_+k)*3+ky)*3+kx];
    wsum[bg*CG_*9 + i] = a;
  }
}

// ---------------- Kernel 3: mu / rstd of pre = gx * sh * sw ---------------
__global__ void k_stats2(const float* __restrict__ x, const float* __restrict__ sh,
                         const float* __restrict__ sw, float* __restrict__ mu,
                         float* __restrict__ rstd){
  int plane = blockIdx.x; int tid=threadIdx.x;
  __shared__ float shl[H_]; __shared__ float swl[W_];
  for (int i=tid;i<H_;i+=256) shl[i]=sh[plane*H_+i];
  for (int i=tid;i<W_;i+=256) swl[i]=sw[plane*W_+i];
  __syncthreads();
  const float4* xp = (const float4*)(x + (size_t)plane*HW_);
  float s=0, s2=0;
  for (int i4=tid; i4<HW_/4; i4+=256){
    int p = i4*4; int h=p/W_, w=p%W_;
    float4 v = xp[i4];
    float shv = shl[h];
    float p0 = v.x*shv*swl[w], p1=v.y*shv*swl[w+1];
    float p2 = v.z*shv*swl[w+2], p3=v.w*shv*swl[w+3];
    s  += p0+p1+p2+p3;
    s2 += p0*p0+p1*p1+p2*p2+p3*p3;
  }
  __shared__ float rs[4], rs2[4];
  #pragma unroll
  for (int off=32; off>0; off>>=1){ s += __shfl_down(s,off,64); s2 += __shfl_down(s2,off,64); }
  int wv=tid>>6, lane=tid&63;
  if (lane==0){ rs[wv]=s; rs2[wv]=s2; }
  __syncthreads();
  if (tid==0){
    float S1=rs[0]+rs[1]+rs[2]+rs[3], S2=rs2[0]+rs2[1]+rs2[2]+rs2[3];
    float m = S1*(1.0f/HW_);
    float v = S2*(1.0f/HW_)-m*m;
    mu[plane]=m; rstd[plane]=rsqrtf(v+EPSV);
  }
}

// ---------------- Kernel 4: alpha and weight constant ---------------------
__global__ void k_coef(const float* __restrict__ x21, const float* __restrict__ gnw,
                       const float* __restrict__ gnb, const float* __restrict__ mu,
                       const float* __restrict__ rstd, const float* __restrict__ bsum,
                       float* __restrict__ alpha, float* __restrict__ wconst){
  int bg = blockIdx.x; int tid=threadIdx.x;
  float contrib = 0.f;
  if (tid < CG_){
    int plane = bg*CG_+tid;
    float t21 = x21[plane];
    alpha[plane] = t21*gnw[tid]*rstd[plane];
    contrib = t21*(gnb[tid] - mu[plane]*rstd[plane]*gnw[tid]);
  }
  #pragma unroll
  for (int off=8; off>0; off>>=1) contrib += __shfl_down(contrib, off, 64);
  if (tid==0) wconst[bg] = bsum[bg] + contrib;
}

// ---------------- Kernel 5: 8-wave 2-channel weight map + fused out -------
// 512 threads = 8 waves; wave ty handles channels ty*2, ty*2+1 for the same
// 64-slot tile. ALL loads (8 wide float4 + boundary scalars for BOTH
// channels) issue straight-line up front (~60 live regs, below the 64 spill
// cliff that killed the 4-channel unroll). Chain per thread: 2 stages.
// XCD swizzle; shfl edges; LDS coeff staging; 8-way LDS partial exchange.
__global__ __launch_bounds__(512) void k_weights(
    const float* __restrict__ x, const float* __restrict__ sh,
    const float* __restrict__ sw, const float* __restrict__ alpha,
    const float* __restrict__ wsum, const float* __restrict__ wconst,
    float* __restrict__ wout, float* __restrict__ out){
  int wgid = blockIdx.x + blockIdx.y*gridDim.x;        // dispatch order (x fastest)
  int swz  = (wgid & 7)*(NTILE_*NG_/8) + (wgid >> 3);  // bijective: 20736%8==0
  int bg   = swz / NTILE_;
  int tile = swz % NTILE_;
  int tid = threadIdx.x;
  int ty = tid>>6, lane = tid&63;
  int i4 = tile*64 + lane;
  bool ok = (i4 < HW4_);
  int i4c = ok ? i4 : (HW4_-1);          // clamped for safe addresses
  int w4 = i4c % W4_, h = i4c / W4_;
  int p  = i4c*4;
  bool hm=(h>0), hp=(h<H_-1), wm=(w4>0), wp=(w4<W4_-1);
  const float4 z4 = {0.f,0.f,0.f,0.f};

  // ---- stage per-block coefficients into LDS ----
  __shared__ float wsl[CG_*9];
  __shared__ float all[CG_];
  __shared__ float shl[CG_][2];
  int h0 = (tile*64) / W4_;              // block spans h0 .. h0+1 at most
  if (tid < CG_*9) wsl[tid] = wsum[bg*CG_*9 + tid];
  else if (tid < CG_*9 + CG_) all[tid - CG_*9] = alpha[bg*CG_ + (tid - CG_*9)];
  else if (tid < CG_*9 + CG_ + 2*CG_){
    int t = tid - CG_*9 - CG_;
    int c = t>>1, r = t&1;
    int hh = h0 + r; if (hh > H_-1) hh = H_-1;
    shl[c][r] = sh[(bg*CG_+c)*H_ + hh];
  }
  __syncthreads();

  int cA = ty*2, cB = ty*2+1;
  const float* xpA = x + (size_t)(bg*CG_+cA)*HW_;
  const float* xpB = xpA + HW_;

  // ---- ALL wide loads up front (max MLP) ----
  float4 v0A = *(const float4*)(xpA + p);
  float4 vmA = hm ? *(const float4*)(xpA + p - W_) : z4;
  float4 vpA = hp ? *(const float4*)(xpA + p + W_) : z4;
  float4 swA = *(const float4*)(&sw[(bg*CG_+cA)*W_ + w4*4]);
  float4 v0B = *(const float4*)(xpB + p);
  float4 vmB = hm ? *(const float4*)(xpB + p - W_) : z4;
  float4 vpB = hp ? *(const float4*)(xpB + p + W_) : z4;
  float4 swB = *(const float4*)(&sw[(bg*CG_+cB)*W_ + w4*4]);

  // ---- boundary scalars for BOTH channels, issued now ----
  float eAm=0.f,eA0=0.f,eAp=0.f,eBm=0.f,eB0=0.f,eBp=0.f;
  if (lane==0 || lane==63){
    bool L = (lane==0);
    bool en = L ? wm : wp;
    int q = L ? (p-1) : (p+4);
    if (en){
      eA0 = xpA[q]; eB0 = xpB[q];
      if (hm){ eAm = xpA[q-W_]; eBm = xpB[q-W_]; }
      if (hp){ eAp = xpA[q+W_]; eBp = xpB[q+W_]; }
    }
  }

  float4 acc = z4;
  // ================= channel A =================
  {
    float lm = __shfl_up(vmA.w, 1, 64);
    float l0 = __shfl_up(v0A.w, 1, 64);
    float lp = __shfl_up(vpA.w, 1, 64);
    float rm = __shfl_down(vmA.x, 1, 64);
    float r0 = __shfl_down(v0A.x, 1, 64);
    float rp = __shfl_down(vpA.x, 1, 64);
    if (!wm){ lm=0.f; l0=0.f; lp=0.f; }
    if (!wp){ rm=0.f; r0=0.f; rp=0.f; }
    if (lane==0){ lm=eAm; l0=eA0; lp=eAp; }
    else if (lane==63){ rm=eAm; r0=eA0; rp=eAp; }
    float a = all[cA] * shl[cA][h - h0];
    const float* wr = wsl + cA*9;
    float w0=wr[0], w1v=wr[1], w2=wr[2], w3v=wr[3], w4v=wr[4];
    float w5=wr[5], w6=wr[6], w7=wr[7], w8=wr[8];
    acc.x += a*swA.x*v0A.x + w0*lm   + w1v*vmA.x + w2*vmA.y
           + w3v*l0        + w4v*v0A.x + w5*v0A.y
           + w6*lp         + w7*vpA.x + w8*vpA.y;
    acc.y += a*swA.y*v0A.y + w0*vmA.x + w1v*vmA.y + w2*vmA.z
           + w3v*v0A.x     + w4v*v0A.y + w5*v0A.z
           + w6*vpA.x      + w7*vpA.y + w8*vpA.z;
    acc.z += a*swA.z*v0A.z + w0*vmA.y + w1v*vmA.z + w2*vmA.w
           + w3v*v0A.y     + w4v*v0A.z + w5*v0A.w
           + w6*vpA.y      + w7*vpA.z + w8*vpA.w;
    acc.w += a*swA.w*v0A.w + w0*vmA.z + w1v*vmA.w + w2*rm
           + w3v*v0A.z     + w4v*v0A.w + w5*r0
           + w6*vpA.z      + w7*vpA.w + w8*rp;
  }
  // ================= channel B =================
  {
    float lm = __shfl_up(vmB.w, 1, 64);
    float l0 = __shfl_up(v0B.w, 1, 64);
    float lp = __shfl_up(vpB.w, 1, 64);
    float rm = __shfl_down(vmB.x, 1, 64);
    float r0 = __shfl_down(v0B.x, 1, 64);
    float rp = __shfl_down(vpB.x, 1, 64);
    if (!wm){ lm=0.f; l0=0.f; lp=0.f; }
    if (!wp){ rm=0.f; r0=0.f; rp=0.f; }
    if (lane==0){ lm=eBm; l0=eB0; lp=eBp; }
    else if (lane==63){ rm=eBm; r0=eB0; rp=eBp; }
    float a = all[cB] * shl[cB][h - h0];
    const float* wr = wsl + cB*9;
    float w0=wr[0], w1v=wr[1], w2=wr[2], w3v=wr[3], w4v=wr[4];
    float w5=wr[5], w6=wr[6], w7=wr[7], w8=wr[8];
    acc.x += a*swB.x*v0B.x + w0*lm   + w1v*vmB.x + w2*vmB.y
           + w3v*l0        + w4v*v0B.x + w5*v0B.y
           + w6*lp         + w7*vpB.x + w8*vpB.y;
    acc.y += a*swB.y*v0B.y + w0*vmB.x + w1v*vmB.y + w2*vmB.z
           + w3v*v0B.x     + w4v*v0B.y + w5*v0B.z
           + w6*vpB.x      + w7*vpB.y + w8*vpB.z;
    acc.z += a*swB.z*v0B.z + w0*vmB.y + w1v*vmB.z + w2*vmB.w
           + w3v*v0B.y     + w4v*v0B.z + w5*v0B.w
           + w6*vpB.y      + w7*vpB.z + w8*vpB.w;
    acc.w += a*swB.w*v0B.w + w0*vmB.z + w1v*vmB.w + w2*rm
           + w3v*v0B.z     + w4v*v0B.w + w5*r0
           + w6*vpB.z      + w7*vpB.w + w8*rp;
  }

  __shared__ float4 part[8][64];
  part[ty][lane] = acc;
  __syncthreads();

  float wc = wconst[bg];
  float4 tot;
  {
    float4 q0 = part[0][lane], q1 = part[1][lane];
    float4 q2 = part[2][lane], q3 = part[3][lane];
    float4 q4 = part[4][lane], q5 = part[5][lane];
    float4 q6 = part[6][lane], q7 = part[7][lane];
    tot.x = ((q0.x+q1.x)+(q2.x+q3.x)) + ((q4.x+q5.x)+(q6.x+q7.x)) + wc;
    tot.y = ((q0.y+q1.y)+(q2.y+q3.y)) + ((q4.y+q5.y)+(q6.y+q7.y)) + wc;
    tot.z = ((q0.z+q1.z)+(q2.z+q3.z)) + ((q4.z+q5.z)+(q6.z+q7.z)) + wc;
    tot.w = ((q0.w+q1.w)+(q2.w+q3.w)) + ((q4.w+q5.w)+(q6.w+q7.w)) + wc;
  }

  if (ty==0 && ok) *(float4*)(wout + (size_t)bg*HW_ + p) = tot;

  float4 gv;
  gv.x = sigf(tot.x); gv.y = sigf(tot.y); gv.z = sigf(tot.z); gv.w = sigf(tot.w);
  int b = bg>>3, g = bg&7;
  if (ok){
    {
      float4 cv = *(const float4*)(xpA + p);   // L1-hot reload
      float* ob = out + (size_t)(b*128 + cA*8 + g)*HW_ + p;
      float4 o; float s;
      s = cv.x*gv.x; o.x = cv.x + s*sigf(s);
      s = cv.y*gv.y; o.y = cv.y + s*sigf(s);
      s = cv.z*gv.z; o.z = cv.z + s*sigf(s);
      s = cv.w*gv.w; o.w = cv.w + s*sigf(s);
      *(float4*)ob = o;
    }
    {
      float4 cv = *(const float4*)(xpB + p);
      float* ob = out + (size_t)(b*128 + cB*8 + g)*HW_ + p;
      float4 o; float s;
      s = cv.x*gv.x; o.x = cv.x + s*sigf(s);
      s = cv.y*gv.y; o.y = cv.y + s*sigf(s);
      s = cv.z*gv.z; o.z = cv.z + s*sigf(s);
      s = cv.w*gv.w; o.w = cv.w + s*sigf(s);
      *(float4*)ob = o;
    }
  }
}

// ---------------- Kernel 6: detection-region conv fixup -------------------
// one block per (b, idx, co): 2048 blocks x 64 threads
__global__ void k_fix(const float* __restrict__ x, const float* __restrict__ wout,
                      const int* __restrict__ det,
                      const float* __restrict__ cw0, const float* __restrict__ cb0,
                      const float* __restrict__ cw1, const float* __restrict__ cb1,
                      const float* __restrict__ cw2, const float* __restrict__ cb2,
                      const float* __restrict__ cw3, const float* __restrict__ cb3,
                      float* __restrict__ out){
  int blk = blockIdx.x;
  int co = blk & 31;
  int bi = blk >> 5;
  int b = bi>>2, idx = bi&3;
  int cx = det[(b*S_+idx)*4+0], cy = det[(b*S_+idx)*4+1];
  if (!(cy>=2 && cy<H_-2 && cx>=2 && cx<W_-2)) return;   // uniform per block
  int ys = cy-2, xs = cx-2;  // in-bounds given validity
  int k = 2*idx+3, pad = idx+1, kk = k*k;
  const float* cw = idx==0?cw0: idx==1?cw1: idx==2?cw2:cw3;
  const float* cb = idx==0?cb0: idx==1?cb1: idx==2?cb2:cb3;
  __shared__ float reg[32*25];
  __shared__ float wl[32*81];
  int tid = threadIdx.x;
  for (int t=tid;t<800;t+=64){
    int ci=t/25, r=t%25, ry=r/5, rx=r%5;
    int g = idx*2 + (ci>>4), cg = ci&15;
    int bg = b*G_+g; int plane = bg*CG_+cg;
    int p = (ys+ry)*W_ + xs+rx;
    reg[t] = x[(size_t)plane*HW_+p]*sigf(wout[(size_t)bg*HW_+p]);
  }
  for (int t=tid;t<32*kk;t+=64) wl[t] = cw[co*32*kk + t];
  __syncthreads();
  // lanes 0..24: pixels, ci 0..15 ; lanes 25..49: same pixels, ci 16..31
  int pix = (tid<25)?tid:(tid-25);
  int half = (tid<25)?0:1;
  float acc = 0.f;
  if (tid < 50){
    int oy = pix/5, ox = pix%5;
    for (int ci=half*16; ci<half*16+16; ++ci){
      const float* wr = wl + ci*kk;
      const float* rr = reg + ci*25;
      #pragma unroll
      for (int iy=0; iy<5; ++iy){
        int ky = iy-oy+pad;
        if ((unsigned)ky >= (unsigned)k) continue;
        #pragma unroll
        for (int ix=0; ix<5; ++ix){
          int kx = ix-ox+pad;
          if ((unsigned)kx >= (unsigned)k) continue;
          acc += wr[ky*k+kx]*rr[iy*5+ix];
        }
      }
    }
  }
  float other = __shfl(acc, tid+25, 64);
  if (tid < 25){
    float tot = cb[co] + acc + other;
    int oy = pix/5, ox = pix%5;
    int g = idx*2 + (co>>4), cg = co&15;
    int bg = b*G_+g; int plane = bg*CG_+cg;
    int p = (ys+oy)*W_ + xs+ox;
    float xv = x[(size_t)plane*HW_+p];
    out[(size_t)(b*128 + cg*8 + g)*HW_+p] = xv + tot*sigf(tot);
  }
}

extern "C" void kernel_launch(void* const* d_in, const int* in_sizes, int n_in,
                              void* d_out, int out_size, void* d_ws, size_t ws_size,
                              hipStream_t stream){
  const float* x   = (const float*)d_in[0];
  const int*   det = (const int*)d_in[1];
  const float* w1  = (const float*)d_in[2];
  const float* b1  = (const float*)d_in[3];
  const float* w3  = (const float*)d_in[4];
  const float* b3  = (const float*)d_in[5];
  const float* gnw = (const float*)d_in[6];
  const float* gnb = (const float*)d_in[7];
  const float* cw0 = (const float*)d_in[8];  const float* cb0 = (const float*)d_in[9];
  const float* cw1 = (const float*)d_in[10]; const float* cb1 = (const float*)d_in[11];
  const float* cw2 = (const float*)d_in[12]; const float* cb2 = (const float*)d_in[13];
  const float* cw3 = (const float*)d_in[14]; const float* cb3 = (const float*)d_in[15];

  float* ws = (float*)d_ws;
  float* xh    = ws;                 // PC_*H_
  float* xw    = xh + PC_*H_;        // PC_*W_
  float* sh    = xw + PC_*W_;        // PC_*H_
  float* sw    = sh + PC_*H_;        // PC_*W_
  float* mu    = sw + PC_*W_;        // PC_
  float* rstd  = mu + PC_;           // PC_
  float* x21   = rstd + PC_;         // PC_
  float* alpha = x21 + PC_;          // PC_
  float* wsum  = alpha + PC_;        // NG_*144
  float* bsum  = wsum + NG_*144;     // NG_
  float* wconst= bsum + NG_;         // NG_
  float* wout  = wconst + NG_;       // NG_*HW_
  float* outp  = (float*)d_out;

  k_stats1<<<PC_,256,0,stream>>>(x, xh, xw);
  k_prep<<<NG_,256,0,stream>>>(x, xh, xw, w1,b1,w3,b3,gnb, sh,sw,x21,wsum,bsum);
  k_stats2<<<PC_,256,0,stream>>>(x, sh, sw, mu, rstd);
  k_coef<<<NG_,64,0,stream>>>(x21,gnw,gnb,mu,rstd,bsum,alpha,wconst);
  dim3 gw(NTILE_, NG_);   // 64 float4-slots per block; swizzled inside
  k_weights<<<gw,512,0,stream>>>(x, sh, sw, alpha, wsum, wconst, wout, outp);
  k_fix<<<B_*S_*32,64,0,stream>>>(x, wout, det, cw0,cb0,cw1,cb1,cw2,cb2,cw3,cb3, outp);
}

// Round 17
// 366.293 us; speedup vs baseline: 1.3464x; 1.3464x over previous
//
#include <hip/hip_runtime.h>
#include <math.h>

#define H_ 152
#define W_ 272
#define HW_ 41344
#define W4_ 68       /* W_/4 */
#define HW4_ 10336   /* HW_/4 */
#define B_ 16
#define G_ 8
#define CG_ 16
#define NG_ 128   /* B*G */
#define PC_ 2048  /* NG*CG */
#define S_ 4
#define EPSV 1e-5f
#define NTILE_ 162   /* ceil(HW4_/64) */

typedef float nfloat4 __attribute__((ext_vector_type(4)));

__device__ __forceinline__ void nt_store4(float* p, float4 v){
  nfloat4 t; t.x=v.x; t.y=v.y; t.z=v.z; t.w=v.w;
  __builtin_nontemporal_store(t, (nfloat4*)p);
}

__device__ __forceinline__ float sigf(float v){ return 1.0f/(1.0f+__expf(-v)); }

// ---------------- Kernel 1: per-plane row means (xh) and col means (xw) ----
__global__ void k_stats1(const float* __restrict__ x, float* __restrict__ xh,
                         float* __restrict__ xw){
  int plane = blockIdx.x;
  const float* xp = x + (size_t)plane*HW_;
  int tid = threadIdx.x, wv = tid>>6, lane = tid&63;
  float ca0[4] = {0,0,0,0};
  float ca1[4] = {0,0,0,0};
  for (int h = wv; h < H_; h += 4){
    const float4* row = (const float4*)(xp + h*W_);
    float4 v0 = row[lane];
    float rs = v0.x+v0.y+v0.z+v0.w;
    ca0[0]+=v0.x; ca0[1]+=v0.y; ca0[2]+=v0.z; ca0[3]+=v0.w;
    if (lane < 4){
      float4 v1 = row[64+lane];
      rs += v1.x+v1.y+v1.z+v1.w;
      ca1[0]+=v1.x; ca1[1]+=v1.y; ca1[2]+=v1.z; ca1[3]+=v1.w;
    }
    #pragma unroll
    for (int off=32; off>0; off>>=1) rs += __shfl_down(rs, off, 64);
    if (lane==0) xh[plane*H_ + h] = rs * (1.0f/W_);
  }
  __shared__ float cs[4][W_];
  #pragma unroll
  for (int j=0;j<4;++j) cs[wv][lane*4+j] = ca0[j];
  if (lane<4){
    #pragma unroll
    for (int j=0;j<4;++j) cs[wv][256+lane*4+j] = ca1[j];
  }
  __syncthreads();
  for (int w=tid; w<W_; w+=256)
    xw[plane*W_ + w] = (cs[0][w]+cs[1][w]+cs[2][w]+cs[3][w]) * (1.0f/H_);
}

// ---------------- Kernel 2: sh/sw gates, x21 softmax, collapsed filter -----
__global__ void k_prep(const float* __restrict__ x,
                       const float* __restrict__ xh, const float* __restrict__ xw,
                       const float* __restrict__ w1, const float* __restrict__ b1,
                       const float* __restrict__ w3, const float* __restrict__ b3,
                       const float* __restrict__ gnb,
                       float* __restrict__ sh, float* __restrict__ sw,
                       float* __restrict__ x21, float* __restrict__ wsum,
                       float* __restrict__ bsum){
  int bg = blockIdx.x; int tid = threadIdx.x;
  __shared__ float xhl[CG_][H_];
  __shared__ float xwl[CG_][W_];
  __shared__ float w1l[CG_*CG_];
  __shared__ float b1l[CG_];
  __shared__ float Tk[CG_], R0[CG_], RL[CG_], C0[CG_], CL[CG_];
  __shared__ float crn[CG_][4];
  __shared__ float mx2[CG_], x11l[CG_];
  for (int i=tid;i<CG_*CG_;i+=256) w1l[i]=w1[i];
  if (tid < CG_) b1l[tid]=b1[tid];
  for (int i=tid;i<CG_*H_;i+=256){ int c=i/H_, h=i%H_; xhl[c][h]=xh[(bg*CG_+c)*H_+h]; }
  for (int i=tid;i<CG_*W_;i+=256){ int c=i/W_, w=i%W_; xwl[c][w]=xw[(bg*CG_+c)*W_+w]; }
  __syncthreads();
  // 1x1 conv + sigmoid on the row/col mean vectors
  for (int i=tid;i<CG_*H_;i+=256){
    int c=i/H_, h=i%H_;
    float a=b1l[c];
    #pragma unroll
    for (int k=0;k<CG_;++k) a += w1l[c*CG_+k]*xhl[k][h];
    sh[(bg*CG_+c)*H_+h] = sigf(a);
  }
  for (int i=tid;i<CG_*W_;i+=256){
    int c=i/W_, w=i%W_;
    float a=b1l[c];
    #pragma unroll
    for (int k=0;k<CG_;++k) a += w1l[c*CG_+k]*xwl[k][w];
    sw[(bg*CG_+c)*W_+w] = sigf(a);
  }
  // exact mean of 3x3-conv output via total/row/col/corner sums
  if (tid < CG_){
    int k=tid;
    float t=0;
    for (int h=0;h<H_;++h) t += xhl[k][h];
    Tk[k] = t * W_;
    R0[k] = xhl[k][0]*W_; RL[k]=xhl[k][H_-1]*W_;
    C0[k] = xwl[k][0]*H_; CL[k]=xwl[k][W_-1]*H_;
    const float* xp = x + (size_t)(bg*CG_+k)*HW_;
    crn[k][0]=xp[0]; crn[k][1]=xp[W_-1];
    crn[k][2]=xp[(size_t)(H_-1)*W_]; crn[k][3]=xp[(size_t)(H_-1)*W_+W_-1];
  }
  __syncthreads();
  if (tid < CG_){
    int c=tid;
    float acc=0;
    for (int k=0;k<CG_;++k){
      #pragma unroll
      for (int ky=0;ky<3;++ky){ int dy=ky-1;
        #pragma unroll
        for (int kx=0;kx<3;++kx){ int dx=kx-1;
          float s = Tk[k];
          if (dy==1) s -= R0[k]; else if (dy==-1) s -= RL[k];
          if (dx==1) s -= C0[k]; else if (dx==-1) s -= CL[k];
          if (dy==1 && dx==1) s += crn[k][0];
          else if (dy==1 && dx==-1) s += crn[k][1];
          else if (dy==-1 && dx==1) s += crn[k][2];
          else if (dy==-1 && dx==-1) s += crn[k][3];
          acc += w3[((c*CG_+k)*3+ky)*3+kx]*s;
        }
      }
    }
    mx2[c] = b3[c] + acc*(1.0f/HW_);
  }
  __syncthreads();
  if (tid==0){
    float m=mx2[0]; for (int c=1;c<CG_;++c) m=fmaxf(m,mx2[c]);
    float ssum=0.f; float e[CG_];
    for (int c=0;c<CG_;++c){ e[c]=__expf(mx2[c]-m); ssum+=e[c]; }
    for (int c=0;c<CG_;++c) x21[bg*CG_+c]=e[c]/ssum;
    // x11 = softmax(mean(x1)) = softmax(gn_b) exactly
    float m2=gnb[0]; for (int c=1;c<CG_;++c) m2=fmaxf(m2,gnb[c]);
    float s2=0.f; float e2[CG_];
    for (int c=0;c<CG_;++c){ e2[c]=__expf(gnb[c]-m2); s2+=e2[c]; }
    float bs=0.f;
    for (int c=0;c<CG_;++c){ x11l[c]=e2[c]/s2; bs += (e2[c]/s2)*b3[c]; }
    bsum[bg]=bs;
  }
  __syncthreads();
  for (int i=tid;i<CG_*9;i+=256){
    int k=i/9, r=i%9; int ky=r/3, kx=r%3;
    float a=0;
    for (int c=0;c<CG_;++c) a += x11l[c]*w3[((c*CG_+k)*3+ky)*3+kx];
    wsum[bg*CG_*9 + i] = a;
  }
}

// ---------------- Kernel 3: mu / rstd of pre = gx * sh * sw ---------------
// REVERSED plane order: stats1 just streamed x 0..2047; L3 (256 MB) holds the
// tail. Reading back-to-front converts much of the fetch into L3 hits.
__global__ void k_stats2(const float* __restrict__ x, const float* __restrict__ sh,
                         const float* __restrict__ sw, float* __restrict__ mu,
                         float* __restrict__ rstd){
  int plane = (PC_-1) - blockIdx.x; int tid=threadIdx.x;
  __shared__ float shl[H_]; __shared__ float swl[W_];
  for (int i=tid;i<H_;i+=256) shl[i]=sh[plane*H_+i];
  for (int i=tid;i<W_;i+=256) swl[i]=sw[plane*W_+i];
  __syncthreads();
  const float4* xp = (const float4*)(x + (size_t)plane*HW_);
  float s=0, s2=0;
  for (int i4=tid; i4<HW_/4; i4+=256){
    int p = i4*4; int h=p/W_, w=p%W_;
    float4 v = xp[i4];
    float shv = shl[h];
    float p0 = v.x*shv*swl[w], p1=v.y*shv*swl[w+1];
    float p2 = v.z*shv*swl[w+2], p3=v.w*shv*swl[w+3];
    s  += p0+p1+p2+p3;
    s2 += p0*p0+p1*p1+p2*p2+p3*p3;
  }
  __shared__ float rs[4], rs2[4];
  #pragma unroll
  for (int off=32; off>0; off>>=1){ s += __shfl_down(s,off,64); s2 += __shfl_down(s2,off,64); }
  int wv=tid>>6, lane=tid&63;
  if (lane==0){ rs[wv]=s; rs2[wv]=s2; }
  __syncthreads();
  if (tid==0){
    float S1=rs[0]+rs[1]+rs[2]+rs[3], S2=rs2[0]+rs2[1]+rs2[2]+rs2[3];
    float m = S1*(1.0f/HW_);
    float v = S2*(1.0f/HW_)-m*m;
    mu[plane]=m; rstd[plane]=rsqrtf(v+EPSV);
  }
}

// ---------------- Kernel 4: alpha and weight constant ---------------------
__global__ void k_coef(const float* __restrict__ x21, const float* __restrict__ gnw,
                       const float* __restrict__ gnb, const float* __restrict__ mu,
                       const float* __restrict__ rstd, const float* __restrict__ bsum,
                       float* __restrict__ alpha, float* __restrict__ wconst){
  int bg = blockIdx.x; int tid=threadIdx.x;
  float contrib = 0.f;
  if (tid < CG_){
    int plane = bg*CG_+tid;
    float t21 = x21[plane];
    alpha[plane] = t21*gnw[tid]*rstd[plane];
    contrib = t21*(gnb[tid] - mu[plane]*rstd[plane]*gnw[tid]);
  }
  #pragma unroll
  for (int off=8; off>0; off>>=1) contrib += __shfl_down(contrib, off, 64);
  if (tid==0) wconst[bg] = bsum[bg] + contrib;
}

// ---------------- Kernel 5: 4-wave channel-split weight map + fused out ---
// r14 structure + the edge scalars moved INTO the prefetch set: in iteration
// j everything for channel c is already resident, so the FMA chain issues no
// vmcnt(0) that would drain the c+1 prefetch (vmcnt waits oldest-first; the
// in-iteration edge loads were the newest ops and forced a full drain).
// Nontemporal stores keep the streaming out/wout writes from evicting x.
__global__ void k_weights(const float* __restrict__ x, const float* __restrict__ sh,
                          const float* __restrict__ sw, const float* __restrict__ alpha,
                          const float* __restrict__ wsum, const float* __restrict__ wconst,
                          float* __restrict__ wout, float* __restrict__ out){
  int wgid = blockIdx.x + blockIdx.y*gridDim.x;        // dispatch order (x fastest)
  int swz  = (wgid & 7)*(NTILE_*NG_/8) + (wgid >> 3);  // bijective: 20736%8==0
  int bg   = swz / NTILE_;
  int tile = swz % NTILE_;
  int tid = threadIdx.x;
  int ty = tid>>6, lane = tid&63;
  int i4 = tile*64 + lane;
  bool ok = (i4 < HW4_);
  int i4c = ok ? i4 : (HW4_-1);          // clamped for safe addresses
  int w4 = i4c % W4_, h = i4c / W4_;
  int p  = i4c*4;
  bool hm=(h>0), hp=(h<H_-1), wm=(w4>0), wp=(w4<W4_-1);
  const float4 z4 = {0.f,0.f,0.f,0.f};

  // ---- stage per-block coefficients into LDS ----
  __shared__ float wsl[CG_*9];
  __shared__ float all[CG_];
  __shared__ float shl[CG_][2];
  int h0 = (tile*64) / W4_;              // block spans h0 .. h0+1 at most
  if (tid < CG_*9) wsl[tid] = wsum[bg*CG_*9 + tid];
  else if (tid < CG_*9 + CG_) all[tid - CG_*9] = alpha[bg*CG_ + (tid - CG_*9)];
  else if (tid < CG_*9 + CG_ + 2*CG_){
    int t = tid - CG_*9 - CG_;
    int c = t>>1, r = t&1;
    int hh = h0 + r; if (hh > H_-1) hh = H_-1;
    shl[c][r] = sh[(bg*CG_+c)*H_ + hh];
  }
  __syncthreads();

  // edge-lane constants (same every channel)
  bool eact = (lane==0 || lane==63);
  bool eL   = (lane==0);
  bool een  = eact && (eL ? wm : wp);
  int  eq   = eL ? (p-1) : (p+4);

  float4 acc = z4;
  int cbase = ty*4;
  // ---- prime: channel cbase wides + edge scalars ----
  const float* xp0 = x + (size_t)(bg*CG_ + cbase)*HW_;
  float4 v0 = *(const float4*)(xp0 + p);
  float4 vm = hm ? *(const float4*)(xp0 + p - W_) : z4;
  float4 vp = hp ? *(const float4*)(xp0 + p + W_) : z4;
  float4 swv = *(const float4*)(&sw[(bg*CG_+cbase)*W_ + w4*4]);
  float em=0.f, e0=0.f, ep=0.f;
  if (een){
    e0 = xp0[eq];
    if (hm) em = xp0[eq-W_];
    if (hp) ep = xp0[eq+W_];
  }

  #pragma unroll 1
  for (int j=0;j<4;++j){
    int c = cbase + j;
    // ---- prefetch channel c+1: wides AND edge scalars ----
    float4 n0=z4, nm=z4, np=z4, nsw=z4;
    float fm=0.f, f0=0.f, fp=0.f;
    if (j<3){
      const float* xn = x + (size_t)(bg*CG_+c+1)*HW_;
      n0 = *(const float4*)(xn + p);
      nm = hm ? *(const float4*)(xn + p - W_) : z4;
      np = hp ? *(const float4*)(xn + p + W_) : z4;
      nsw = *(const float4*)(&sw[(bg*CG_+c+1)*W_ + w4*4]);
      if (een){
        f0 = xn[eq];
        if (hm) fm = xn[eq-W_];
        if (hp) fp = xn[eq+W_];
      }
    }
    // ---- edges from neighbor lanes (all current data resident) ----
    float lm = __shfl_up(vm.w, 1, 64);
    float l0 = __shfl_up(v0.w, 1, 64);
    float lp = __shfl_up(vp.w, 1, 64);
    float rm = __shfl_down(vm.x, 1, 64);
    float r0 = __shfl_down(v0.x, 1, 64);
    float rp = __shfl_down(vp.x, 1, 64);
    if (!wm){ lm=0.f; l0=0.f; lp=0.f; }
    if (!wp){ rm=0.f; r0=0.f; rp=0.f; }
    if (lane==0){ lm=em; l0=e0; lp=ep; }
    else if (lane==63){ rm=em; r0=e0; rp=ep; }
    float a = all[c] * shl[c][h - h0];
    const float* wr = wsl + c*9;
    float w0=wr[0], w1v=wr[1], w2=wr[2], w3v=wr[3], w4v=wr[4];
    float w5=wr[5], w6=wr[6], w7=wr[7], w8=wr[8];
    acc.x += a*swv.x*v0.x + w0*lm   + w1v*vm.x + w2*vm.y
           + w3v*l0       + w4v*v0.x + w5*v0.y
           + w6*lp        + w7*vp.x + w8*vp.y;
    acc.y += a*swv.y*v0.y + w0*vm.x + w1v*vm.y + w2*vm.z
           + w3v*v0.x     + w4v*v0.y + w5*v0.z
           + w6*vp.x      + w7*vp.y + w8*vp.z;
    acc.z += a*swv.z*v0.z + w0*vm.y + w1v*vm.z + w2*vm.w
           + w3v*v0.y     + w4v*v0.z + w5*v0.w
           + w6*vp.y      + w7*vp.z + w8*vp.w;
    acc.w += a*swv.w*v0.w + w0*vm.z + w1v*vm.w + w2*rm
           + w3v*v0.z     + w4v*v0.w + w5*r0
           + w6*vp.z      + w7*vp.w + w8*rp;
    // ---- rotate (vmcnt wait for prefetch lands here, after the FMAs) ----
    v0 = n0; vm = nm; vp = np; swv = nsw;
    em = fm; e0 = f0; ep = fp;
  }

  __shared__ float4 part[4][64];
  part[ty][lane] = acc;
  __syncthreads();

  float4 p0v = part[0][lane], p1v = part[1][lane];
  float4 p2v = part[2][lane], p3v = part[3][lane];
  float wc = wconst[bg];
  float4 tot;
  tot.x = p0v.x+p1v.x+p2v.x+p3v.x + wc;
  tot.y = p0v.y+p1v.y+p2v.y+p3v.y + wc;
  tot.z = p0v.z+p1v.z+p2v.z+p3v.z + wc;
  tot.w = p0v.w+p1v.w+p2v.w+p3v.w + wc;

  if (ty==0 && ok)
    nt_store4(wout + (size_t)bg*HW_ + p, tot);

  float4 gv;
  gv.x = sigf(tot.x); gv.y = sigf(tot.y); gv.z = sigf(tot.z); gv.w = sigf(tot.w);
  int b = bg>>3, g = bg&7;
  if (ok){
    #pragma unroll 1
    for (int j=0;j<4;++j){
      int c = ty*4 + j;
      const float* xp = x + (size_t)(bg*CG_+c)*HW_;
      float4 cv = *(const float4*)(xp + p);   // L1/L2-hot reload
      float* ob = out + (size_t)(b*128 + c*8 + g)*HW_ + p;
      float4 o; float s;
      s = cv.x*gv.x; o.x = cv.x + s*sigf(s);
      s = cv.y*gv.y; o.y = cv.y + s*sigf(s);
      s = cv.z*gv.z; o.z = cv.z + s*sigf(s);
      s = cv.w*gv.w; o.w = cv.w + s*sigf(s);
      nt_store4(ob, o);
    }
  }
}

// ---------------- Kernel 6: detection-region conv fixup -------------------
// one block per (b, idx, co): 2048 blocks x 64 threads
__global__ void k_fix(const float* __restrict__ x, const float* __restrict__ wout,
                      const int* __restrict__ det,
                      const float* __restrict__ cw0, const float* __restrict__ cb0,
                      const float* __restrict__ cw1, const float* __restrict__ cb1,
                      const float* __restrict__ cw2, const float* __restrict__ cb2,
                      const float* __restrict__ cw3, const float* __restrict__ cb3,
                      float* __restrict__ out){
  int blk = blockIdx.x;
  int co = blk & 31;
  int bi = blk >> 5;
  int b = bi>>2, idx = bi&3;
  int cx = det[(b*S_+idx)*4+0], cy = det[(b*S_+idx)*4+1];
  if (!(cy>=2 && cy<H_-2 && cx>=2 && cx<W_-2)) return;   // uniform per block
  int ys = cy-2, xs = cx-2;  // in-bounds given validity
  int k = 2*idx+3, pad = idx+1, kk = k*k;
  const float* cw = idx==0?cw0: idx==1?cw1: idx==2?cw2:cw3;
  const float* cb = idx==0?cb0: idx==1?cb1: idx==2?cb2:cb3;
  __shared__ float reg[32*25];
  __shared__ float wl[32*81];
  int tid = threadIdx.x;
  for (int t=tid;t<800;t+=64){
    int ci=t/25, r=t%25, ry=r/5, rx=r%5;
    int g = idx*2 + (ci>>4), cg = ci&15;
    int bg = b*G_+g; int plane = bg*CG_+cg;
    int p = (ys+ry)*W_ + xs+rx;
    reg[t] = x[(size_t)plane*HW_+p]*sigf(wout[(size_t)bg*HW_+p]);
  }
  for (int t=tid;t<32*kk;t+=64) wl[t] = cw[co*32*kk + t];
  __syncthreads();
  // lanes 0..24: pixels, ci 0..15 ; lanes 25..49: same pixels, ci 16..31
  int pix = (tid<25)?tid:(tid-25);
  int half = (tid<25)?0:1;
  float acc = 0.f;
  if (tid < 50){
    int oy = pix/5, ox = pix%5;
    for (int ci=half*16; ci<half*16+16; ++ci){
      const float* wr = wl + ci*kk;
      const float* rr = reg + ci*25;
      #pragma unroll
      for (int iy=0; iy<5; ++iy){
        int ky = iy-oy+pad;
        if ((unsigned)ky >= (unsigned)k) continue;
        #pragma unroll
        for (int ix=0; ix<5; ++ix){
          int kx = ix-ox+pad;
          if ((unsigned)kx >= (unsigned)k) continue;
          acc += wr[ky*k+kx]*rr[iy*5+ix];
        }
      }
    }
  }
  float other = __shfl(acc, tid+25, 64);
  if (tid < 25){
    float tot = cb[co] + acc + other;
    int oy = pix/5, ox = pix%5;
    int g = idx*2 + (co>>4), cg = co&15;
    int bg = b*G_+g; int plane = bg*CG_+cg;
    int p = (ys+oy)*W_ + xs+ox;
    float xv = x[(size_t)plane*HW_+p];
    out[(size_t)(b*128 + cg*8 + g)*HW_+p] = xv + tot*sigf(tot);
  }
}

extern "C" void kernel_launch(void* const* d_in, const int* in_sizes, int n_in,
                              void* d_out, int out_size, void* d_ws, size_t ws_size,
                              hipStream_t stream){
  const float* x   = (const float*)d_in[0];
  const int*   det = (const int*)d_in[1];
  const float* w1  = (const float*)d_in[2];
  const float* b1  = (const float*)d_in[3];
  const float* w3  = (const float*)d_in[4];
  const float* b3  = (const float*)d_in[5];
  const float* gnw = (const float*)d_in[6];
  const float* gnb = (const float*)d_in[7];
  const float* cw0 = (const float*)d_in[8];  const float* cb0 = (const float*)d_in[9];
  const float* cw1 = (const float*)d_in[10]; const float* cb1 = (const float*)d_in[11];
  const float* cw2 = (const float*)d_in[12]; const float* cb2 = (const float*)d_in[13];
  const float* cw3 = (const float*)d_in[14]; const float* cb3 = (const float*)d_in[15];

  float* ws = (float*)d_ws;
  float* xh    = ws;                 // PC_*H_
  float* xw    = xh + PC_*H_;        // PC_*W_
  float* sh    = xw + PC_*W_;        // PC_*H_
  float* sw    = sh + PC_*H_;        // PC_*W_
  float* mu    = sw + PC_*W_;        // PC_
  float* rstd  = mu + PC_;           // PC_
  float* x21   = rstd + PC_;         // PC_
  float* alpha = x21 + PC_;          // PC_
  float* wsum  = alpha + PC_;        // NG_*144
  float* bsum  = wsum + NG_*144;     // NG_
  float* wconst= bsum + NG_;         // NG_
  float* wout  = wconst + NG_;       // NG_*HW_
  float* outp  = (float*)d_out;

  k_stats1<<<PC_,256,0,stream>>>(x, xh, xw);
  k_prep<<<NG_,256,0,stream>>>(x, xh, xw, w1,b1,w3,b3,gnb, sh,sw,x21,wsum,bsum);
  k_stats2<<<PC_,256,0,stream>>>(x, sh, sw, mu, rstd);
  k_coef<<<NG_,64,0,stream>>>(x21,gnw,gnb,mu,rstd,bsum,alpha,wconst);
  dim3 gw(NTILE_, NG_);   // 64 float4-slots per block; swizzled inside
  k_weights<<<gw,256,0,stream>>>(x, sh, sw, alpha, wsum, wconst, wout, outp);
  k_fix<<<B_*S_*32,64,0,stream>>>(x, wout, det, cw0,cb0,cw1,cb1,cw2,cb2,cw3,cb3, outp);
}